// Round 10
// baseline (215.007 us; speedup 1.0000x reference)
//
#include <hip/hip_runtime.h>
#include <hip/hip_bf16.h>
#include <hip/hip_cooperative_groups.h>
namespace cg = cooperative_groups;

#define B_    32
#define H_    256
#define W_    256
#define ROWS  8            // output rows per tile
#define LR    (ROWS + 2)   // 10 LDS rows (halo)
#define LCP   68           // padded cols -> row stride 136 16B-units (mult of 8 keeps XOR bijective)
#define RSTR  (LCP*2)      // 136 units per row
#define BUFU  (LR*RSTR)    // 1360 s16x8 units per LDS buffer
#define NTILES (B_*(H_/ROWS)*(W_/64))   // 4096
#define CGRID  512
#define NTF    (NTILES/CGRID)           // 8 tiles per block (fused)
// ws layout: [64,5184)=packA | [8192,16384)=pmax floats

typedef float f32x4 __attribute__((ext_vector_type(4)));
typedef short s16x8 __attribute__((ext_vector_type(8)));

__device__ inline unsigned short f2bf(float f){
  __hip_bfloat16 h = __float2bfloat16(f);
  return __builtin_bit_cast(unsigned short, h);
}

// exact round-half-even of x/s via reciprocal + exact fma residual correction
__device__ inline float quant1(float v, float rinv, float s, float hs){
  float q0 = rintf(v * rinv);
  float d  = fmaf(q0, -s, v);        // ~ s*(v/s - q0), one rounding
  q0 += (d >  hs) ? 1.f : 0.f;
  q0 -= (d < -hs) ? 1.f : 0.f;
  return fminf(fmaxf(q0, -127.f), 127.f);
}

// tile id t: hg fastest (consecutive tiles vertically adjacent), then strip, b
__device__ __forceinline__ void tile_decode(int t, int& b, int& w0, int& h0){
  int hg = t & 31; int r = t >> 5;
  w0 = (r & 3) * 64; b = r >> 2; h0 = hg * ROWS;
}

__device__ __forceinline__ void build_packA(const float* __restrict__ wq,
                                            unsigned short* __restrict__ packA,
                                            int l){
  int co = l & 15;
  int g  = l >> 4;
  for (int mm2 = 0; mm2 < 5; ++mm2){
    for (int i = 0; i < 8; ++i){
      int kappa = g*8 + i;
      int tap = 2*mm2 + (kappa >> 4);
      int ci  = kappa & 15;
      float v = (tap <= 8) ? wq[(co*16 + ci)*9 + tap] : 0.f;
      packA[(mm2*64 + l)*8 + i] = f2bf(v);
    }
  }
}

// ---- Q helpers: NGRP (row,half) groups starting at LDS row RBASE (verified r8)
template<int NGRP, int RBASE>
__device__ __forceinline__ void q_load_t(const float* __restrict__ x,
                                         int b, int w0, int h0,
                                         int tid, int lane, int wid,
                                         float v[][8], float tv[8]){
  const int KMAX  = (NGRP + 7) / 8;
  const int NTAIL = (NGRP / 2) * 4;
  const int c = lane;
  const int win = w0 - 1 + c;
  const bool colok = (unsigned)win < 256u;
  #pragma unroll
  for (int k = 0; k < KMAX; ++k){
    int gi = wid + 8*k;
    bool act = gi < NGRP;
    int r = RBASE + (gi >> 1), half = gi & 1;
    int hin = h0 + r - 1;
    bool rowok = (unsigned)hin < 256u;
    bool ok = act && rowok && colok;
    const float* p = x + ((size_t)(b*16 + half*8) << 16) + (size_t)(rowok ? hin : 0)*256 + win;
    #pragma unroll
    for (int ci = 0; ci < 8; ++ci)
      v[k][ci] = ok ? p[(size_t)ci << 16] : 0.f;
  }
  if (tid >= 448 && tid < 448 + NTAIL){
    int t = tid - 448;
    int t_c = 64 + (t & 1), t_half = (t >> 1) & 1, t_r = RBASE + (t >> 2);
    int hin = h0 + t_r - 1;
    bool rowok = (unsigned)hin < 256u;
    int twin = w0 - 1 + t_c;
    bool ok = rowok && ((unsigned)twin < 256u);
    const float* p = x + ((size_t)(b*16 + t_half*8) << 16) + (size_t)(rowok ? hin : 0)*256 + twin;
    #pragma unroll
    for (int ci = 0; ci < 8; ++ci)
      tv[ci] = ok ? p[(size_t)ci << 16] : 0.f;
  }
}

template<int NGRP, int RBASE>
__device__ __forceinline__ void q_write_t(s16x8* ldsv, int bufoff,
                                          int tid, int lane, int wid,
                                          const float v[][8], const float tv[8],
                                          float rinv, float s, float hs){
  const int KMAX  = (NGRP + 7) / 8;
  const int NTAIL = (NGRP / 2) * 4;
  const int c = lane;
  #pragma unroll
  for (int k = 0; k < KMAX; ++k){
    int gi = wid + 8*k;
    if (gi < NGRP){
      int r = RBASE + (gi >> 1), half = gi & 1;
      s16x8 qv;
      #pragma unroll
      for (int ci = 0; ci < 8; ++ci)
        qv[ci] = (short)f2bf(quant1(v[k][ci], rinv, s, hs));
      int u = (r*RSTR + c*2 + half) ^ ((c >> 2) & 7);
      ldsv[bufoff + u] = qv;
    }
  }
  if (tid >= 448 && tid < 448 + NTAIL){
    int t = tid - 448;
    int t_c = 64 + (t & 1), t_half = (t >> 1) & 1, t_r = RBASE + (t >> 2);
    s16x8 qv;
    #pragma unroll
    for (int ci = 0; ci < 8; ++ci)
      qv[ci] = (short)f2bf(quant1(tv[ci], rinv, s, hs));
    int u = (t_r*RSTR + t_c*2 + t_half) ^ ((t_c >> 2) & 7);
    ldsv[bufoff + u] = qv;
  }
}

// ---- C phase: one output row per wave, 4 col-chunks x 5 MFMAs (verified r6-9)
__device__ __forceinline__ void c_phase(const s16x8* ldsv, int bufoff,
                                        const s16x8 A[5], const int kr[5], const int kw[5],
                                        int lane, int wid, int b, int w0, int h0,
                                        const float sc[4], const float bb[4],
                                        float* __restrict__ out){
  const int colg = lane & 15;
  const int g    = lane >> 4;
  const int hlf  = g & 1;
  f32x4 acc[4] = {};
  #pragma unroll
  for (int n = 0; n < 4; ++n){
    #pragma unroll
    for (int m = 0; m < 5; ++m){
      int cc = n*16 + colg + kw[m];
      int u = ((wid + kr[m])*RSTR + cc*2 + hlf) ^ ((cc >> 2) & 7);
      acc[n] = __builtin_amdgcn_mfma_f32_16x16x32_bf16(A[m], ldsv[bufoff + u], acc[n], 0, 0, 0);
    }
  }
  const int h = h0 + wid;
  #pragma unroll
  for (int j = 0; j < 4; ++j){
    const int co = g*4 + j;
    float* op = out + ((size_t)(b*16 + co) << 16) + h*256 + w0 + colg;
    #pragma unroll
    for (int n = 0; n < 4; ++n)
      __builtin_nontemporal_store(acc[n][j] * sc[j] + bb[j], op + n*16);
  }
}

// === fused cooperative kernel: absmax -> grid.sync -> quant+conv pipeline ===
// NOTE: __launch_bounds__(512) ONLY — r9's ",4" capped VGPR at 64 and caused
// ~1.6GB of scratch spill traffic (the 211us regression). VGPR must be free
// to reach ~96-128; if >128, coop launch fails and we take the r8 fallback.
__global__ __launch_bounds__(512) void fused_kernel(const float* __restrict__ x,
                                                    const float* __restrict__ wq,
                                                    const float* __restrict__ sw,
                                                    const float* __restrict__ bias,
                                                    float* __restrict__ pmax,
                                                    unsigned short* __restrict__ packA,
                                                    float* __restrict__ out,
                                                    int n4){
  __shared__ __align__(16) unsigned short lds[2*LR*LCP*16];
  __shared__ float redmax[8];
  s16x8* ldsv = reinterpret_cast<s16x8*>(lds);

  const int tid  = threadIdx.x;
  const int lane = tid & 63;
  const int wid  = tid >> 6;     // 0..7
  const int bid  = blockIdx.x;

  // ---- phase 1: grid-stride absmax ----
  {
    int idx = bid*blockDim.x + tid;
    int stride = gridDim.x*blockDim.x;
    float m = 0.f;
    for (int i = idx; i < n4; i += stride){
      float4 vv = reinterpret_cast<const float4*>(x)[i];
      m = fmaxf(m, fmaxf(fmaxf(fabsf(vv.x), fabsf(vv.y)), fmaxf(fabsf(vv.z), fabsf(vv.w))));
    }
    #pragma unroll
    for (int off = 32; off > 0; off >>= 1)
      m = fmaxf(m, __shfl_xor(m, off));
    if (lane == 0) redmax[wid] = m;
    __syncthreads();
    if (tid == 0)
      pmax[bid] = fmaxf(fmaxf(fmaxf(redmax[0], redmax[1]), fmaxf(redmax[2], redmax[3])),
                        fmaxf(fmaxf(redmax[4], redmax[5]), fmaxf(redmax[6], redmax[7])));
    if (bid == 0 && tid < 64) build_packA(wq, packA, tid);
  }
  __threadfence();

  // ---- issue tile t0's global loads BEFORE the grid barrier (latency hides) ----
  const int t0 = (bid & 7)*512 + (bid >> 3)*NTF;   // XCD-chunked, bijective
  int b, w0, h0;
  float v[3][8], tv[8];
  tile_decode(t0, b, w0, h0);
  q_load_t<20,0>(x, b, w0, h0, tid, lane, wid, v, tv);

  cg::this_grid().sync();

  // ---- global max from 512 partials ----
  {
    float4 pv = reinterpret_cast<const float4*>(pmax)[tid & 127];
    float m = fmaxf(fmaxf(pv.x, pv.y), fmaxf(pv.z, pv.w));
    #pragma unroll
    for (int off = 32; off > 0; off >>= 1)
      m = fmaxf(m, __shfl_xor(m, off));
    __syncthreads();              // redmax reuse: phase-1 reads done
    if (lane == 0) redmax[wid] = m;
    __syncthreads();
  }
  float gm = redmax[0];
  #pragma unroll
  for (int i = 1; i < 8; ++i) gm = fmaxf(gm, redmax[i]);

  const float s    = gm * 0.0078125f;   // max|x| / 128
  const float rinv = 1.0f / s;
  const float hs   = 0.5f * s;

  // loop-invariant A fragments, tap geometry, dequant constants
  const int g   = lane >> 4;
  const int tlg = g >> 1;
  int kr[5], kw[5];
  #pragma unroll
  for (int mm = 0; mm < 5; ++mm){
    int t = 2*mm + tlg; if (t > 8) t = 8;  // tap 9: A=0, read tap 8 (finite)
    kr[mm] = (t*11) >> 5;
    kw[mm] = t - kr[mm]*3;
  }
  s16x8 A[5];
  const s16x8* pA = reinterpret_cast<const s16x8*>(packA);
  #pragma unroll
  for (int mm = 0; mm < 5; ++mm) A[mm] = pA[mm*64 + lane];
  float sc[4], bb[4];
  #pragma unroll
  for (int j = 0; j < 4; ++j){
    sc[j] = s * sw[g*4 + j];
    bb[j] = bias[g*4 + j];
  }

  q_write_t<20,0>(ldsv, 0, tid, lane, wid, v, tv, rinv, s, hs);
  __syncthreads();

  for (int k = 0; k < NTF; ++k){
    const int cur = k & 1;
    if (k < NTF-1){
      int b2, w2, h2; tile_decode(t0 + k + 1, b2, w2, h2);
      q_load_t<16,2>(x, b2, w2, h2, tid, lane, wid, v, tv);  // rows 2..9 only
      // halo-row reuse: tile k rows 8,9 == tile k+1 rows 0,1 (swizzle row-local)
      if (tid < 2*RSTR){
        int rr = tid >= RSTR;
        int cc = tid - rr*RSTR;
        ldsv[(cur^1)*BUFU + rr*RSTR + cc] = ldsv[cur*BUFU + (8+rr)*RSTR + cc];
      }
    }
    tile_decode(t0 + k, b, w0, h0);
    c_phase(ldsv, cur*BUFU, A, kr, kw, lane, wid, b, w0, h0, sc, bb, out);
    if (k < NTF-1)
      q_write_t<16,2>(ldsv, (cur^1)*BUFU, tid, lane, wid, v, tv, rinv, s, hs);
    __syncthreads();
  }
}

// === fallback two-kernel path (r8 structure, passed @85.9us) ===
__global__ __launch_bounds__(256) void absmax_kernel(const float* __restrict__ x,
                                                     const float* __restrict__ wq,
                                                     float* __restrict__ pmax,
                                                     unsigned short* __restrict__ packA,
                                                     int n4){
  __shared__ float red[4];
  int idx = blockIdx.x*blockDim.x + threadIdx.x;
  int stride = gridDim.x*blockDim.x;
  float m = 0.f;
  for (int i = idx; i < n4; i += stride){
    float4 v = reinterpret_cast<const float4*>(x)[i];
    m = fmaxf(m, fmaxf(fmaxf(fabsf(v.x), fabsf(v.y)), fmaxf(fabsf(v.z), fabsf(v.w))));
  }
  #pragma unroll
  for (int off = 32; off > 0; off >>= 1)
    m = fmaxf(m, __shfl_xor(m, off));
  int lane = threadIdx.x & 63, wid = threadIdx.x >> 6;
  if (lane == 0) red[wid] = m;
  __syncthreads();
  if (threadIdx.x == 0)
    pmax[blockIdx.x] = fmaxf(fmaxf(red[0], red[1]), fmaxf(red[2], red[3]));
  if (blockIdx.x == 0 && threadIdx.x < 64) build_packA(wq, packA, threadIdx.x);
}

__global__ __launch_bounds__(512) void fconv_kernel(const float* __restrict__ x,
                                                    const float* __restrict__ sw,
                                                    const float* __restrict__ bias,
                                                    const float* __restrict__ pmax,
                                                    const unsigned short* __restrict__ packA,
                                                    float* __restrict__ out){
  __shared__ __align__(16) unsigned short lds[2*LR*LCP*16];
  __shared__ float redmax[8];
  s16x8* ldsv = reinterpret_cast<s16x8*>(lds);
  const int tid  = threadIdx.x;
  const int lane = tid & 63;
  const int wid  = tid >> 6;
  const int bid = blockIdx.x;
  const int t0  = (bid & 7)*512 + (bid >> 3)*4;
  int b, w0, h0;
  float v[3][8], tv[8];
  tile_decode(t0, b, w0, h0);
  q_load_t<20,0>(x, b, w0, h0, tid, lane, wid, v, tv);
  float4 pv = reinterpret_cast<const float4*>(pmax)[tid];
  float m = fmaxf(fmaxf(pv.x, pv.y), fmaxf(pv.z, pv.w));
  #pragma unroll
  for (int off = 32; off > 0; off >>= 1)
    m = fmaxf(m, __shfl_xor(m, off));
  if (lane == 0) redmax[wid] = m;
  __syncthreads();
  float gm = redmax[0];
  #pragma unroll
  for (int i = 1; i < 8; ++i) gm = fmaxf(gm, redmax[i]);
  const float s    = gm * 0.0078125f;
  const float rinv = 1.0f / s;
  const float hs   = 0.5f * s;
  const int g   = lane >> 4;
  const int tlg = g >> 1;
  int kr[5], kw[5];
  #pragma unroll
  for (int mm = 0; mm < 5; ++mm){
    int t = 2*mm + tlg; if (t > 8) t = 8;
    kr[mm] = (t*11) >> 5;
    kw[mm] = t - kr[mm]*3;
  }
  s16x8 A[5];
  const s16x8* pA = reinterpret_cast<const s16x8*>(packA);
  #pragma unroll
  for (int mm = 0; mm < 5; ++mm) A[mm] = pA[mm*64 + lane];
  float sc[4], bb[4];
  #pragma unroll
  for (int j = 0; j < 4; ++j){
    sc[j] = s * sw[g*4 + j];
    bb[j] = bias[g*4 + j];
  }
  q_write_t<20,0>(ldsv, 0, tid, lane, wid, v, tv, rinv, s, hs);
  __syncthreads();
  for (int k = 0; k < 4; ++k){
    const int cur = k & 1;
    if (k < 3){
      int b2, w2, h2; tile_decode(t0 + k + 1, b2, w2, h2);
      q_load_t<16,2>(x, b2, w2, h2, tid, lane, wid, v, tv);
      if (tid < 2*RSTR){
        int rr = tid >= RSTR;
        int cc = tid - rr*RSTR;
        ldsv[(cur^1)*BUFU + rr*RSTR + cc] = ldsv[cur*BUFU + (8+rr)*RSTR + cc];
      }
    }
    tile_decode(t0 + k, b, w0, h0);
    c_phase(ldsv, cur*BUFU, A, kr, kw, lane, wid, b, w0, h0, sc, bb, out);
    if (k < 3)
      q_write_t<16,2>(ldsv, (cur^1)*BUFU, tid, lane, wid, v, tv, rinv, s, hs);
    __syncthreads();
  }
}

extern "C" void kernel_launch(void* const* d_in, const int* in_sizes, int n_in,
                              void* d_out, int out_size, void* d_ws, size_t ws_size,
                              hipStream_t stream){
  const float* x    = (const float*)d_in[0];
  const float* wq   = (const float*)d_in[1];
  const float* sw   = (const float*)d_in[2];
  const float* bias = (const float*)d_in[3];
  float* out = (float*)d_out;
  unsigned short* packA = (unsigned short*)((char*)d_ws + 64);
  float* pmax = (float*)((char*)d_ws + 8192);
  int n4 = (B_*16*H_*W_)/4;

  void* args[] = {(void*)&x, (void*)&wq, (void*)&sw, (void*)&bias,
                  (void*)&pmax, (void*)&packA, (void*)&out, (void*)&n4};
  hipError_t e = hipLaunchCooperativeKernel(reinterpret_cast<void*>(fused_kernel),
                                            dim3(CGRID), dim3(512), args, 0, stream);
  if (e != hipSuccess){
    (void)hipGetLastError();   // clear; fall back to two-kernel path (r8)
    absmax_kernel<<<2048, 256, 0, stream>>>(x, wq, pmax, packA, n4);
    fconv_kernel<<<NTILES/4, 512, 0, stream>>>(x, sw, bias, pmax, packA, out);
  }
}

// Round 11
// 85.858 us; speedup vs baseline: 2.5042x; 2.5042x over previous
//
#include <hip/hip_runtime.h>
#include <hip/hip_bf16.h>

#define B_    32
#define H_    256
#define W_    256
#define ROWS  8            // output rows per tile
#define LR    (ROWS + 2)   // 10 LDS rows (halo)
#define LCP   68           // padded cols -> row stride 136 16B-units (mult of 8 keeps XOR bijective)
#define RSTR  (LCP*2)      // 136 units per row
#define BUFU  (LR*RSTR)    // 1360 s16x8 units per LDS buffer
#define NT    4            // tiles per block (vertically adjacent)
#define NTILES (B_*(H_/ROWS)*(W_/64))   // 4096
// ws layout: [64,5184)=packA | [8192,16384)=pmax[2048] floats

typedef float f32x4 __attribute__((ext_vector_type(4)));
typedef short s16x8 __attribute__((ext_vector_type(8)));

__device__ inline unsigned short f2bf(float f){
  __hip_bfloat16 h = __float2bfloat16(f);
  return __builtin_bit_cast(unsigned short, h);
}

// exact round-half-even of x/s via reciprocal + exact fma residual correction
__device__ inline float quant1(float v, float rinv, float s, float hs){
  float q0 = rintf(v * rinv);
  float d  = fmaf(q0, -s, v);        // ~ s*(v/s - q0), one rounding
  q0 += (d >  hs) ? 1.f : 0.f;
  q0 -= (d < -hs) ? 1.f : 0.f;
  return fminf(fmaxf(q0, -127.f), 127.f);
}

// tile id t: hg fastest (consecutive tiles vertically adjacent), then strip, b
__device__ __forceinline__ void tile_decode(int t, int& b, int& w0, int& h0){
  int hg = t & 31; int r = t >> 5;
  w0 = (r & 3) * 64; b = r >> 2; h0 = hg * ROWS;
}

__device__ __forceinline__ void build_packA(const float* __restrict__ wq,
                                            unsigned short* __restrict__ packA,
                                            int l){
  int co = l & 15;
  int g  = l >> 4;
  for (int mm2 = 0; mm2 < 5; ++mm2){
    for (int i = 0; i < 8; ++i){
      int kappa = g*8 + i;
      int tap = 2*mm2 + (kappa >> 4);
      int ci  = kappa & 15;
      float v = (tap <= 8) ? wq[(co*16 + ci)*9 + tap] : 0.f;
      packA[(mm2*64 + l)*8 + i] = f2bf(v);
    }
  }
}

// --- kernel 1: per-block max|x| -> pmax[bid] + packA build in block 0 (r8) ---
__global__ __launch_bounds__(256) void absmax_kernel(const float* __restrict__ x,
                                                     const float* __restrict__ wq,
                                                     float* __restrict__ pmax,
                                                     unsigned short* __restrict__ packA,
                                                     int n4){
  __shared__ float red[4];
  int idx = blockIdx.x*blockDim.x + threadIdx.x;
  int stride = gridDim.x*blockDim.x;
  float m = 0.f;
  for (int i = idx; i < n4; i += stride){
    float4 v = reinterpret_cast<const float4*>(x)[i];
    m = fmaxf(m, fmaxf(fmaxf(fabsf(v.x), fabsf(v.y)), fmaxf(fabsf(v.z), fabsf(v.w))));
  }
  #pragma unroll
  for (int off = 32; off > 0; off >>= 1)
    m = fmaxf(m, __shfl_xor(m, off));
  int lane = threadIdx.x & 63, wid = threadIdx.x >> 6;
  if (lane == 0) red[wid] = m;
  __syncthreads();
  if (threadIdx.x == 0)
    pmax[blockIdx.x] = fmaxf(fmaxf(red[0], red[1]), fmaxf(red[2], red[3]));
  if (blockIdx.x == 0 && threadIdx.x < 64) build_packA(wq, packA, threadIdx.x);
}

// ---- Q helpers: NGRP (row,half) groups starting at LDS row RBASE (verified r8)
template<int NGRP, int RBASE>
__device__ __forceinline__ void q_load_t(const float* __restrict__ x,
                                         int b, int w0, int h0,
                                         int tid, int lane, int wid,
                                         float v[][8], float tv[8]){
  const int KMAX  = (NGRP + 7) / 8;
  const int NTAIL = (NGRP / 2) * 4;
  const int c = lane;
  const int win = w0 - 1 + c;
  const bool colok = (unsigned)win < 256u;
  #pragma unroll
  for (int k = 0; k < KMAX; ++k){
    int gi = wid + 8*k;
    bool act = gi < NGRP;
    int r = RBASE + (gi >> 1), half = gi & 1;
    int hin = h0 + r - 1;
    bool rowok = (unsigned)hin < 256u;
    bool ok = act && rowok && colok;
    const float* p = x + ((size_t)(b*16 + half*8) << 16) + (size_t)(rowok ? hin : 0)*256 + win;
    #pragma unroll
    for (int ci = 0; ci < 8; ++ci)
      v[k][ci] = ok ? p[(size_t)ci << 16] : 0.f;
  }
  if (tid >= 448 && tid < 448 + NTAIL){
    int t = tid - 448;
    int t_c = 64 + (t & 1), t_half = (t >> 1) & 1, t_r = RBASE + (t >> 2);
    int hin = h0 + t_r - 1;
    bool rowok = (unsigned)hin < 256u;
    int twin = w0 - 1 + t_c;
    bool ok = rowok && ((unsigned)twin < 256u);
    const float* p = x + ((size_t)(b*16 + t_half*8) << 16) + (size_t)(rowok ? hin : 0)*256 + twin;
    #pragma unroll
    for (int ci = 0; ci < 8; ++ci)
      tv[ci] = ok ? p[(size_t)ci << 16] : 0.f;
  }
}

template<int NGRP, int RBASE>
__device__ __forceinline__ void q_write_t(s16x8* ldsv, int bufoff,
                                          int tid, int lane, int wid,
                                          const float v[][8], const float tv[8],
                                          float rinv, float s, float hs){
  const int KMAX  = (NGRP + 7) / 8;
  const int NTAIL = (NGRP / 2) * 4;
  const int c = lane;
  #pragma unroll
  for (int k = 0; k < KMAX; ++k){
    int gi = wid + 8*k;
    if (gi < NGRP){
      int r = RBASE + (gi >> 1), half = gi & 1;
      s16x8 qv;
      #pragma unroll
      for (int ci = 0; ci < 8; ++ci)
        qv[ci] = (short)f2bf(quant1(v[k][ci], rinv, s, hs));
      int u = (r*RSTR + c*2 + half) ^ ((c >> 2) & 7);
      ldsv[bufoff + u] = qv;
    }
  }
  if (tid >= 448 && tid < 448 + NTAIL){
    int t = tid - 448;
    int t_c = 64 + (t & 1), t_half = (t >> 1) & 1, t_r = RBASE + (t >> 2);
    s16x8 qv;
    #pragma unroll
    for (int ci = 0; ci < 8; ++ci)
      qv[ci] = (short)f2bf(quant1(tv[ci], rinv, s, hs));
    int u = (t_r*RSTR + t_c*2 + t_half) ^ ((t_c >> 2) & 7);
    ldsv[bufoff + u] = qv;
  }
}

// ---- C phase: one output row per wave, 4 col-chunks x 5 MFMAs (verified r6-10)
__device__ __forceinline__ void c_phase(const s16x8* ldsv, int bufoff,
                                        const s16x8 A[5], const int kr[5], const int kw[5],
                                        int lane, int wid, int b, int w0, int h0,
                                        const float sc[4], const float bb[4],
                                        float* __restrict__ out){
  const int colg = lane & 15;
  const int g    = lane >> 4;
  const int hlf  = g & 1;
  f32x4 acc[4] = {};
  #pragma unroll
  for (int n = 0; n < 4; ++n){
    #pragma unroll
    for (int m = 0; m < 5; ++m){
      int cc = n*16 + colg + kw[m];
      int u = ((wid + kr[m])*RSTR + cc*2 + hlf) ^ ((cc >> 2) & 7);
      acc[n] = __builtin_amdgcn_mfma_f32_16x16x32_bf16(A[m], ldsv[bufoff + u], acc[n], 0, 0, 0);
    }
  }
  const int h = h0 + wid;
  #pragma unroll
  for (int j = 0; j < 4; ++j){
    const int co = g*4 + j;
    float* op = out + ((size_t)(b*16 + co) << 16) + h*256 + w0 + colg;
    #pragma unroll
    for (int n = 0; n < 4; ++n)
      __builtin_nontemporal_store(acc[n][j] * sc[j] + bb[j], op + n*16);
  }
}

// --- kernel 2: persistent fused quant+conv, double-buffered, halo-row reuse ---
// amdgpu_waves_per_eu(2,4): override the LDS-derived occupancy heuristic that
// pinned this shape (512thr + 44KB LDS) at VGPR=64 (r9/r10 evidence), which
// spilled/serialized the ~100-reg software pipeline. Cap -> 256, target <=4
// waves/EU; expect ~96-128 VGPR and the cross-tile pipeline to materialize.
__global__ __launch_bounds__(512) __attribute__((amdgpu_waves_per_eu(2, 4)))
void fconv_kernel(const float* __restrict__ x,
                  const float* __restrict__ sw,
                  const float* __restrict__ bias,
                  const float* __restrict__ pmax,
                  const unsigned short* __restrict__ packA,
                  float* __restrict__ out){
  __shared__ __align__(16) unsigned short lds[2*LR*LCP*16];
  __shared__ float redmax[8];
  s16x8* ldsv = reinterpret_cast<s16x8*>(lds);

  const int tid  = threadIdx.x;
  const int lane = tid & 63;
  const int wid  = tid >> 6;     // 0..7

  // XCD-chunked: 8 chunks x 512 tiles; within chunk, NT vertically-adjacent tiles
  const int bid = blockIdx.x;
  const int t0  = (bid & 7)*512 + (bid >> 3)*NT;

  int b, w0, h0;
  float v[3][8], tv[8];

  // prologue tile t0: issue global loads FIRST (pmax reduce hides under them)
  tile_decode(t0, b, w0, h0);
  q_load_t<20,0>(x, b, w0, h0, tid, lane, wid, v, tv);

  // global-max reduce over 2048 partials (8KB, L2-resident)
  float4 pv = reinterpret_cast<const float4*>(pmax)[tid];
  float m = fmaxf(fmaxf(pv.x, pv.y), fmaxf(pv.z, pv.w));
  #pragma unroll
  for (int off = 32; off > 0; off >>= 1)
    m = fmaxf(m, __shfl_xor(m, off));
  if (lane == 0) redmax[wid] = m;
  __syncthreads();
  float gm = redmax[0];
  #pragma unroll
  for (int i = 1; i < 8; ++i) gm = fmaxf(gm, redmax[i]);

  const float s    = gm * 0.0078125f;   // max|x| / 128
  const float rinv = 1.0f / s;
  const float hs   = 0.5f * s;

  // loop-invariant A fragments, tap geometry, dequant constants
  const int g   = lane >> 4;
  const int tlg = g >> 1;
  int kr[5], kw[5];
  #pragma unroll
  for (int mm = 0; mm < 5; ++mm){
    int t = 2*mm + tlg; if (t > 8) t = 8;  // tap 9: A=0, read tap 8 (finite)
    kr[mm] = (t*11) >> 5;
    kw[mm] = t - kr[mm]*3;
  }
  s16x8 A[5];
  const s16x8* pA = reinterpret_cast<const s16x8*>(packA);
  #pragma unroll
  for (int mm = 0; mm < 5; ++mm) A[mm] = pA[mm*64 + lane];
  float sc[4], bb[4];
  #pragma unroll
  for (int j = 0; j < 4; ++j){
    sc[j] = s * sw[g*4 + j];
    bb[j] = bias[g*4 + j];
  }

  q_write_t<20,0>(ldsv, 0, tid, lane, wid, v, tv, rinv, s, hs);
  __syncthreads();

  #pragma unroll
  for (int k = 0; k < NT; ++k){
    const int cur = k & 1;
    if (k < NT-1){
      int b2, w2, h2; tile_decode(t0 + k + 1, b2, w2, h2);
      q_load_t<16,2>(x, b2, w2, h2, tid, lane, wid, v, tv);  // rows 2..9 only
      // halo-row reuse: tile k rows 8,9 == tile k+1 rows 0,1 (swizzle row-local)
      if (tid < 2*RSTR){
        int rr = tid >= RSTR;
        int cc = tid - rr*RSTR;
        ldsv[(cur^1)*BUFU + rr*RSTR + cc] = ldsv[cur*BUFU + (8+rr)*RSTR + cc];
      }
    }
    tile_decode(t0 + k, b, w0, h0);
    c_phase(ldsv, cur*BUFU, A, kr, kw, lane, wid, b, w0, h0, sc, bb, out);
    if (k < NT-1)
      q_write_t<16,2>(ldsv, (cur^1)*BUFU, tid, lane, wid, v, tv, rinv, s, hs);
    __syncthreads();
  }
}

extern "C" void kernel_launch(void* const* d_in, const int* in_sizes, int n_in,
                              void* d_out, int out_size, void* d_ws, size_t ws_size,
                              hipStream_t stream){
  const float* x    = (const float*)d_in[0];
  const float* wq   = (const float*)d_in[1];
  const float* sw   = (const float*)d_in[2];
  const float* bias = (const float*)d_in[3];
  float* out = (float*)d_out;
  unsigned short* packA = (unsigned short*)((char*)d_ws + 64);
  float* pmax = (float*)((char*)d_ws + 8192);

  absmax_kernel<<<2048, 256, 0, stream>>>(x, wq, pmax, packA, (B_*16*H_*W_)/4);
  fconv_kernel<<<NTILES/NT, 512, 0, stream>>>(x, sw, bias, pmax, packA, out);
}

// Round 12
// 82.640 us; speedup vs baseline: 2.6017x; 1.0389x over previous
//
#include <hip/hip_runtime.h>
#include <hip/hip_bf16.h>

#define B_    32
#define H_    256
#define W_    256
#define ROWS  8            // output rows per tile
#define LR    (ROWS + 2)   // 10 LDS rows (halo)
#define LCP   68           // padded cols -> row stride 136 16B-units (mult of 8 keeps XOR bijective)
#define RSTR  (LCP*2)      // 136 units per row
#define BUFU  (LR*RSTR)    // 1360 s16x8 units per LDS buffer
#define NT    8            // tiles per block (vertically adjacent; start mod 32 in {0,8,16,24} so no wrap)
#define NTILES (B_*(H_/ROWS)*(W_/64))   // 4096
// ws layout: [64,5184)=packA | [8192,16384)=pmax[2048] floats

typedef float f32x4 __attribute__((ext_vector_type(4)));
typedef short s16x8 __attribute__((ext_vector_type(8)));

__device__ inline unsigned short f2bf(float f){
  __hip_bfloat16 h = __float2bfloat16(f);
  return __builtin_bit_cast(unsigned short, h);
}

// exact round-half-even of x/s via reciprocal + exact fma residual correction
__device__ inline float quant1(float v, float rinv, float s, float hs){
  float q0 = rintf(v * rinv);
  float d  = fmaf(q0, -s, v);        // ~ s*(v/s - q0), one rounding
  q0 += (d >  hs) ? 1.f : 0.f;
  q0 -= (d < -hs) ? 1.f : 0.f;
  return fminf(fmaxf(q0, -127.f), 127.f);
}

// tile id t: hg fastest (consecutive tiles vertically adjacent), then strip, b
__device__ __forceinline__ void tile_decode(int t, int& b, int& w0, int& h0){
  int hg = t & 31; int r = t >> 5;
  w0 = (r & 3) * 64; b = r >> 2; h0 = hg * ROWS;
}

__device__ __forceinline__ void build_packA(const float* __restrict__ wq,
                                            unsigned short* __restrict__ packA,
                                            int l){
  int co = l & 15;
  int g  = l >> 4;
  for (int mm2 = 0; mm2 < 5; ++mm2){
    for (int i = 0; i < 8; ++i){
      int kappa = g*8 + i;
      int tap = 2*mm2 + (kappa >> 4);
      int ci  = kappa & 15;
      float v = (tap <= 8) ? wq[(co*16 + ci)*9 + tap] : 0.f;
      packA[(mm2*64 + l)*8 + i] = f2bf(v);
    }
  }
}

// --- kernel 1: per-block max|x| -> pmax[bid] + packA build in block 0 (r8) ---
__global__ __launch_bounds__(256) void absmax_kernel(const float* __restrict__ x,
                                                     const float* __restrict__ wq,
                                                     float* __restrict__ pmax,
                                                     unsigned short* __restrict__ packA,
                                                     int n4){
  __shared__ float red[4];
  int idx = blockIdx.x*blockDim.x + threadIdx.x;
  int stride = gridDim.x*blockDim.x;
  float m = 0.f;
  for (int i = idx; i < n4; i += stride){
    float4 v = reinterpret_cast<const float4*>(x)[i];
    m = fmaxf(m, fmaxf(fmaxf(fabsf(v.x), fabsf(v.y)), fmaxf(fabsf(v.z), fabsf(v.w))));
  }
  #pragma unroll
  for (int off = 32; off > 0; off >>= 1)
    m = fmaxf(m, __shfl_xor(m, off));
  int lane = threadIdx.x & 63, wid = threadIdx.x >> 6;
  if (lane == 0) red[wid] = m;
  __syncthreads();
  if (threadIdx.x == 0)
    pmax[blockIdx.x] = fmaxf(fmaxf(red[0], red[1]), fmaxf(red[2], red[3]));
  if (blockIdx.x == 0 && threadIdx.x < 64) build_packA(wq, packA, threadIdx.x);
}

// ---- Q helpers: NGRP (row,half) groups starting at LDS row RBASE (verified r8)
template<int NGRP, int RBASE>
__device__ __forceinline__ void q_load_t(const float* __restrict__ x,
                                         int b, int w0, int h0,
                                         int tid, int lane, int wid,
                                         float v[][8], float tv[8]){
  const int KMAX  = (NGRP + 7) / 8;
  const int NTAIL = (NGRP / 2) * 4;
  const int c = lane;
  const int win = w0 - 1 + c;
  const bool colok = (unsigned)win < 256u;
  #pragma unroll
  for (int k = 0; k < KMAX; ++k){
    int gi = wid + 8*k;
    bool act = gi < NGRP;
    int r = RBASE + (gi >> 1), half = gi & 1;
    int hin = h0 + r - 1;
    bool rowok = (unsigned)hin < 256u;
    bool ok = act && rowok && colok;
    const float* p = x + ((size_t)(b*16 + half*8) << 16) + (size_t)(rowok ? hin : 0)*256 + win;
    #pragma unroll
    for (int ci = 0; ci < 8; ++ci)
      v[k][ci] = ok ? p[(size_t)ci << 16] : 0.f;
  }
  if (tid >= 448 && tid < 448 + NTAIL){
    int t = tid - 448;
    int t_c = 64 + (t & 1), t_half = (t >> 1) & 1, t_r = RBASE + (t >> 2);
    int hin = h0 + t_r - 1;
    bool rowok = (unsigned)hin < 256u;
    int twin = w0 - 1 + t_c;
    bool ok = rowok && ((unsigned)twin < 256u);
    const float* p = x + ((size_t)(b*16 + t_half*8) << 16) + (size_t)(rowok ? hin : 0)*256 + twin;
    #pragma unroll
    for (int ci = 0; ci < 8; ++ci)
      tv[ci] = ok ? p[(size_t)ci << 16] : 0.f;
  }
}

template<int NGRP, int RBASE>
__device__ __forceinline__ void q_write_t(s16x8* ldsv, int bufoff,
                                          int tid, int lane, int wid,
                                          const float v[][8], const float tv[8],
                                          float rinv, float s, float hs){
  const int KMAX  = (NGRP + 7) / 8;
  const int NTAIL = (NGRP / 2) * 4;
  const int c = lane;
  #pragma unroll
  for (int k = 0; k < KMAX; ++k){
    int gi = wid + 8*k;
    if (gi < NGRP){
      int r = RBASE + (gi >> 1), half = gi & 1;
      s16x8 qv;
      #pragma unroll
      for (int ci = 0; ci < 8; ++ci)
        qv[ci] = (short)f2bf(quant1(v[k][ci], rinv, s, hs));
      int u = (r*RSTR + c*2 + half) ^ ((c >> 2) & 7);
      ldsv[bufoff + u] = qv;
    }
  }
  if (tid >= 448 && tid < 448 + NTAIL){
    int t = tid - 448;
    int t_c = 64 + (t & 1), t_half = (t >> 1) & 1, t_r = RBASE + (t >> 2);
    s16x8 qv;
    #pragma unroll
    for (int ci = 0; ci < 8; ++ci)
      qv[ci] = (short)f2bf(quant1(tv[ci], rinv, s, hs));
    int u = (t_r*RSTR + t_c*2 + t_half) ^ ((t_c >> 2) & 7);
    ldsv[bufoff + u] = qv;
  }
}

// ---- C phase: one output row per wave, 4 col-chunks x 5 MFMAs (verified r6-11)
__device__ __forceinline__ void c_phase(const s16x8* ldsv, int bufoff,
                                        const s16x8 A[5], const int kr[5], const int kw[5],
                                        int lane, int wid, int b, int w0, int h0,
                                        const float sc[4], const float bb[4],
                                        float* __restrict__ out){
  const int colg = lane & 15;
  const int g    = lane >> 4;
  const int hlf  = g & 1;
  f32x4 acc[4] = {};
  #pragma unroll
  for (int n = 0; n < 4; ++n){
    #pragma unroll
    for (int m = 0; m < 5; ++m){
      int cc = n*16 + colg + kw[m];
      int u = ((wid + kr[m])*RSTR + cc*2 + hlf) ^ ((cc >> 2) & 7);
      acc[n] = __builtin_amdgcn_mfma_f32_16x16x32_bf16(A[m], ldsv[bufoff + u], acc[n], 0, 0, 0);
    }
  }
  const int h = h0 + wid;
  #pragma unroll
  for (int j = 0; j < 4; ++j){
    const int co = g*4 + j;
    float* op = out + ((size_t)(b*16 + co) << 16) + h*256 + w0 + colg;
    #pragma unroll
    for (int n = 0; n < 4; ++n)
      __builtin_nontemporal_store(acc[n][j] * sc[j] + bb[j], op + n*16);
  }
}

// --- kernel 2: persistent fused quant+conv, double-buffered, halo-row reuse.
// NT=8: 512 blocks = exactly 2/CU co-resident (LDS cap 3/CU) -> no scheduling
// tail; read amplification 1.063 vs 1.096 at NT=4.
__global__ __launch_bounds__(512)
void fconv_kernel(const float* __restrict__ x,
                  const float* __restrict__ sw,
                  const float* __restrict__ bias,
                  const float* __restrict__ pmax,
                  const unsigned short* __restrict__ packA,
                  float* __restrict__ out){
  __shared__ __align__(16) unsigned short lds[2*LR*LCP*16];
  __shared__ float redmax[8];
  s16x8* ldsv = reinterpret_cast<s16x8*>(lds);

  const int tid  = threadIdx.x;
  const int lane = tid & 63;
  const int wid  = tid >> 6;     // 0..7

  // XCD-chunked: 8 chunks x 512 tiles; within chunk, NT vertically-adjacent tiles
  const int bid = blockIdx.x;
  const int t0  = (bid & 7)*512 + (bid >> 3)*NT;

  int b, w0, h0;
  float v[3][8], tv[8];

  // prologue tile t0: issue global loads FIRST (pmax reduce hides under them)
  tile_decode(t0, b, w0, h0);
  q_load_t<20,0>(x, b, w0, h0, tid, lane, wid, v, tv);

  // global-max reduce over 2048 partials (8KB, L2-resident)
  float4 pv = reinterpret_cast<const float4*>(pmax)[tid];
  float m = fmaxf(fmaxf(pv.x, pv.y), fmaxf(pv.z, pv.w));
  #pragma unroll
  for (int off = 32; off > 0; off >>= 1)
    m = fmaxf(m, __shfl_xor(m, off));
  if (lane == 0) redmax[wid] = m;
  __syncthreads();
  float gm = redmax[0];
  #pragma unroll
  for (int i = 1; i < 8; ++i) gm = fmaxf(gm, redmax[i]);

  const float s    = gm * 0.0078125f;   // max|x| / 128
  const float rinv = 1.0f / s;
  const float hs   = 0.5f * s;

  // loop-invariant A fragments, tap geometry, dequant constants
  const int g   = lane >> 4;
  const int tlg = g >> 1;
  int kr[5], kw[5];
  #pragma unroll
  for (int mm = 0; mm < 5; ++mm){
    int t = 2*mm + tlg; if (t > 8) t = 8;  // tap 9: A=0, read tap 8 (finite)
    kr[mm] = (t*11) >> 5;
    kw[mm] = t - kr[mm]*3;
  }
  s16x8 A[5];
  const s16x8* pA = reinterpret_cast<const s16x8*>(packA);
  #pragma unroll
  for (int mm = 0; mm < 5; ++mm) A[mm] = pA[mm*64 + lane];
  float sc[4], bb[4];
  #pragma unroll
  for (int j = 0; j < 4; ++j){
    sc[j] = s * sw[g*4 + j];
    bb[j] = bias[g*4 + j];
  }

  q_write_t<20,0>(ldsv, 0, tid, lane, wid, v, tv, rinv, s, hs);
  __syncthreads();

  #pragma unroll
  for (int k = 0; k < NT; ++k){
    const int cur = k & 1;
    if (k < NT-1){
      int b2, w2, h2; tile_decode(t0 + k + 1, b2, w2, h2);
      q_load_t<16,2>(x, b2, w2, h2, tid, lane, wid, v, tv);  // rows 2..9 only
      // halo-row reuse: tile k rows 8,9 == tile k+1 rows 0,1 (swizzle row-local)
      if (tid < 2*RSTR){
        int rr = tid >= RSTR;
        int cc = tid - rr*RSTR;
        ldsv[(cur^1)*BUFU + rr*RSTR + cc] = ldsv[cur*BUFU + (8+rr)*RSTR + cc];
      }
    }
    tile_decode(t0 + k, b, w0, h0);
    c_phase(ldsv, cur*BUFU, A, kr, kw, lane, wid, b, w0, h0, sc, bb, out);
    if (k < NT-1)
      q_write_t<16,2>(ldsv, (cur^1)*BUFU, tid, lane, wid, v, tv, rinv, s, hs);
    __syncthreads();
  }
}

extern "C" void kernel_launch(void* const* d_in, const int* in_sizes, int n_in,
                              void* d_out, int out_size, void* d_ws, size_t ws_size,
                              hipStream_t stream){
  const float* x    = (const float*)d_in[0];
  const float* wq   = (const float*)d_in[1];
  const float* sw   = (const float*)d_in[2];
  const float* bias = (const float*)d_in[3];
  float* out = (float*)d_out;
  unsigned short* packA = (unsigned short*)((char*)d_ws + 64);
  float* pmax = (float*)((char*)d_ws + 8192);

  absmax_kernel<<<2048, 256, 0, stream>>>(x, wq, pmax, packA, (B_*16*H_*W_)/4);
  fconv_kernel<<<NTILES/NT, 512, 0, stream>>>(x, sw, bias, pmax, packA, out);
}